// Round 22
// baseline (88.105 us; speedup 1.0000x reference)
//
#include <hip/hip_runtime.h>
#include <hip/hip_bf16.h>
#include <stdint.h>

// Problem constants
#define NB    32    // batch
#define CIN   128
#define HH    56
#define WW    56
#define COUT  256

// ws layout: wpack only (bf16, 36*8192 = 294,912 elems)
typedef __attribute__((ext_vector_type(4))) float f32x4;
typedef __attribute__((ext_vector_type(16))) float f32x16;
typedef __attribute__((ext_vector_type(8))) short bf16x8;

__device__ __forceinline__ unsigned short f2bf(float f) {
    union { float f; unsigned u; } v; v.f = f;
    unsigned r = v.u + 0x7FFFu + ((v.u >> 16) & 1u);
    return (unsigned short)(r >> 16);
}

// ---------------------------------------------------------------------------
// build_weight: compose per-output-channel filters.
// wpack layout (R22, for 32x32x16 fragments):
//   [tile(36)][wid(4)][mfrag(2)][kstep(2)][lane(64)][kin(8)]
//   elem = tile*8192 + wid*2048 + mfrag*1024 + kstep*512 + lane*8 + kin
//   where tile = pos*4+cib, o = wid*64 + mfrag*32 + (lane&31),
//   ci = cib*32 + kstep*16 + (lane>>5)*8 + kin.
// A-fragment (v_mfma_f32_32x32x16_bf16): row = lane&31, k = (lane>>5)*8+j —
// derived by strict analogy from the verified 16x16x32 mapping
// (row = lane&15, k = (lane>>4)*8+j). Wave-load stays 16B/lane contiguous.
// ---------------------------------------------------------------------------
__global__ __launch_bounds__(256) void build_weight(
    const float* __restrict__ dict, const float* __restrict__ coef,
    const int* __restrict__ idxw, unsigned short* __restrict__ wpack) {
    int o = blockIdx.x;
    int tid = threadIdx.x;
    bool mode64 = (idxw[1] == 0) && (idxw[3] == 0) && (idxw[5] == 0) &&
                  (idxw[7] == 0) && (idxw[9] == 0) && (idxw[11] == 0) &&
                  (idxw[13] == 0) && (idxw[15] == 0);
    float c[8]; int di[8];
#pragma unroll
    for (int s = 0; s < 8; ++s) {
        c[s]  = coef[o * 8 + s];
        di[s] = mode64 ? idxw[(o * 8 + s) * 2] : idxw[o * 8 + s];
    }
    const int wid = o >> 6, mfrag = (o >> 5) & 1, mloc = o & 31;
    for (int j = tid; j < 9 * 128; j += 256) {
        int pos = j >> 7;          // 0..8
        int ci  = j & 127;
        int kh = pos / 3, kw = pos - kh * 3;
        float v = 0.f;
#pragma unroll
        for (int s = 0; s < 8; ++s)
            v += c[s] * dict[((di[s] * CIN + ci) * 3 + kh) * 3 + kw];
        int tile   = pos * 4 + (ci >> 5);
        int kstep  = (ci >> 4) & 1;
        int kloc8  = (ci >> 3) & 1;
        int kin    = ci & 7;
        wpack[tile * 8192 + wid * 2048 + mfrag * 1024 + kstep * 512 +
              (kloc8 * 32 + mloc) * 8 + kin] = f2bf(v);
    }
}

// ---------------------------------------------------------------------------
// Main: FUSED pack + implicit-GEMM conv (R22 = R19 with 32x32x16 MFMA).
// R19-verified parts kept verbatim: fused batched pack (lane=iw, one wait,
// conflict-free 16B writes), slab [row(3)][ch(16)][iw(64)][kin(8)] stride
// 512 (0-conflict reads), single barrier, XCD swizzle, (256,3), ping-pong A.
// Changed: 8 x mfma_f32_32x32x16_bf16 per tap instead of 16 x 16x16x32 —
// half the MFMA instructions, +15% pipe ceiling (2382 vs 2075 TF measured).
//  - B-frag (32x32x16): col = lane&31, k = (lane>>5)*8+j -> slab read
//    bl0 = Bl[(lane>>5)*512 + (lane&31)*8], imm offs (kh*16+kstep*2)*512
//    + (nfrag*32+kw)*8. Two 512B contiguous chunks/wave-read: conflict-free.
//  - C/D (m74/m101-verified): col = lane&31, row = (r&3)+8*(r>>2)+4*(lane>>5).
//  - acc = f32x16[2][2] = 64 AGPR (same budget as before).
// ---------------------------------------------------------------------------
__global__ __launch_bounds__(256, 3) void conv_mfma(
    const float* __restrict__ x,
    const unsigned short* __restrict__ wpack,
    float* __restrict__ out) {
    // slab: elem = (row*16 + ch)*512 + iw*8 + kin ; +128 pad (junk-col reads)
    __shared__ unsigned short Bl[3 * 16 * 512 + 128];

    int tid  = threadIdx.x;
    int lane = tid & 63;
    int wid  = tid >> 6;       // 0..3 = Cout slice of 64 (and ci-quarter in pack)

    // XCD-bijective swizzle: 1792 = 8 * 224; each XCD gets 4 consecutive b's
    int flat = blockIdx.x;
    int swz  = (flat & 7) * 224 + (flat >> 3);
    int b    = swz / 56;       // 0..31
    int oh   = swz % 56;       // output row

    // A-fragment base (coalesced): af(tile,mfrag,kstep) at
    // ap0 + tile*8192 + mfrag*1024 + kstep*512 ; lane stride 8 elems = 16B.
    const unsigned short* ap0 = wpack + (size_t)wid * 2048 + lane * 8;

    // ---- issue A(tile 0) early: latency hides under the pack phase ----
    bf16x8 af[2][2][2];        // [set][mfrag][kstep]
#pragma unroll
    for (int mfr = 0; mfr < 2; ++mfr)
#pragma unroll
        for (int s = 0; s < 2; ++s)
            af[0][mfr][s] = *(const bf16x8*)(ap0 + mfr * 1024 + s * 512);

    // ---- fused pack: lane = iw, wave = ci-quarter; batched 32-float loads ----
    {
        const int iw = lane;
        const bool vw = (iw >= 1) && (iw <= WW);
        const int w = vw ? iw - 1 : 0;
#pragma unroll
        for (int row = 0; row < 3; ++row) {
            int h = oh + row - 1;
            bool valid = vw && (h >= 0) && (h < HH);
            int hc = h < 0 ? 0 : (h >= HH ? HH - 1 : h);
            const float* px =
                x + (((size_t)b * CIN + wid * 32) * HH + hc) * WW + w;
            float v[32];
#pragma unroll
            for (int j = 0; j < 32; ++j)          // 32 independent loads
                v[j] = px[(size_t)j * (HH * WW)];
#pragma unroll
            for (int c = 0; c < 4; ++c) {         // one wait, 4 vector writes
                bf16x8 pv;
#pragma unroll
                for (int j = 0; j < 8; ++j)
                    pv[j] = valid ? (short)f2bf(v[c * 8 + j]) : (short)0;
                *(bf16x8*)&Bl[(row * 16 + wid * 4 + c) * 512 + iw * 8] = pv;
            }
        }
    }

    f32x16 acc[2][2];          // [mfrag][nfrag] = 64 AGPR
#pragma unroll
    for (int i = 0; i < 2; ++i)
#pragma unroll
        for (int j = 0; j < 2; ++j)
#pragma unroll
            for (int r = 0; r < 16; ++r) acc[i][j][r] = 0.f;

    __syncthreads();   // slab resident; ONLY barrier in the kernel

    const unsigned short* apc = ap0;                       // += 8192/cib
    // B-frag per-lane base: col = lane&31, k-group = lane>>5
    const unsigned short* bl0 = &Bl[(lane >> 5) * 512 + (lane & 31) * 8];

#pragma unroll 2
    for (int cib = 0; cib < 4; ++cib) {
        const unsigned short* bcur = bl0 + cib * 2048;     // ch += 4 per cib

#pragma unroll
        for (int pos = 0; pos < 9; ++pos) {
            const int kh = pos / 3, kw = pos - kh * 3;
            const int cur = (cib + pos) & 1;   // STATIC under unroll-2 cib

            // ---- prefetch A(next step) into the free set (ping-pong) ----
            if (pos < 8) {
#pragma unroll
                for (int mfr = 0; mfr < 2; ++mfr)
#pragma unroll
                    for (int s = 0; s < 2; ++s)
                        af[cur ^ 1][mfr][s] = *(const bf16x8*)(
                            apc + (pos + 1) * 32768 + mfr * 1024 + s * 512);
            } else if (cib < 3) {
#pragma unroll
                for (int mfr = 0; mfr < 2; ++mfr)
#pragma unroll
                    for (int s = 0; s < 2; ++s)
                        af[cur ^ 1][mfr][s] = *(const bf16x8*)(
                            apc + 8192 + mfr * 1024 + s * 512);
            }

            // ---- B fragments from resident slab (imm-offset ds_read) ----
            // elem = (kh*16 + cib*4 + s*2 + (lane>>5))*512
            //        + (nfr*32 + (lane&31) + kw)*8
            bf16x8 bfr[2][2];  // [kstep][nfrag]
#pragma unroll
            for (int s = 0; s < 2; ++s)
#pragma unroll
                for (int nfr = 0; nfr < 2; ++nfr)
                    bfr[s][nfr] = *(const bf16x8*)(
                        bcur + (kh * 16 + s * 2) * 512 + (nfr * 32 + kw) * 8);

            // ---- 8 MFMA (32x32x16) on af[cur] ----
            __builtin_amdgcn_s_setprio(1);
#pragma unroll
            for (int s = 0; s < 2; ++s)
#pragma unroll
                for (int mfr = 0; mfr < 2; ++mfr)
#pragma unroll
                    for (int nfr = 0; nfr < 2; ++nfr)
                        acc[mfr][nfr] = __builtin_amdgcn_mfma_f32_32x32x16_bf16(
                            af[cur][mfr][s], bfr[s][nfr], acc[mfr][nfr], 0, 0, 0);
            __builtin_amdgcn_s_setprio(0);
        }
        apc += 8192;
    }

    // Epilogue: 32x32 C/D layout (m74/m101-verified):
    // col = lane&31, row = (r&3) + 8*(r>>2) + 4*(lane>>5)
#pragma unroll
    for (int nfr = 0; nfr < 2; ++nfr) {
        int ow = nfr * 32 + (lane & 31);
        if (ow < WW) {
#pragma unroll
            for (int mfr = 0; mfr < 2; ++mfr) {
                int ob0 = wid * 64 + mfr * 32 + 4 * (lane >> 5);
#pragma unroll
                for (int r = 0; r < 16; ++r) {
                    int row = (r & 3) + 8 * (r >> 2);
                    out[(((size_t)b * COUT + ob0 + row) * HH + oh) * WW + ow] =
                        acc[mfr][nfr][r];
                }
            }
        }
    }
}

extern "C" void kernel_launch(void* const* d_in, const int* in_sizes, int n_in,
                              void* d_out, int out_size, void* d_ws, size_t ws_size,
                              hipStream_t stream) {
    const float* x    = (const float*)d_in[0];
    const float* dict = (const float*)d_in[1];
    const float* coef = (const float*)d_in[2];
    const int*   idxw = (const int*)d_in[3];
    float* out = (float*)d_out;

    unsigned short* wpack = (unsigned short*)d_ws;

    build_weight<<<dim3(COUT), dim3(256), 0, stream>>>(dict, coef, idxw, wpack);
    conv_mfma<<<dim3(NB * 56), dim3(256), 0, stream>>>(x, wpack, out);
}

// Round 23
// 78.186 us; speedup vs baseline: 1.1269x; 1.1269x over previous
//
#include <hip/hip_runtime.h>
#include <hip/hip_bf16.h>
#include <stdint.h>

// Problem constants
#define NB    32    // batch
#define CIN   128
#define HH    56
#define WW    56
#define COUT  256

// ws layout: wpack only (bf16, 36*8192 = 294,912 elems)
typedef __attribute__((ext_vector_type(4))) float f32x4;
typedef __attribute__((ext_vector_type(8))) short bf16x8;

__device__ __forceinline__ unsigned short f2bf(float f) {
    union { float f; unsigned u; } v; v.f = f;
    unsigned r = v.u + 0x7FFFu + ((v.u >> 16) & 1u);
    return (unsigned short)(r >> 16);
}

// ---------------------------------------------------------------------------
// build_weight: compose per-output-channel filters.
// wpack layout (R13-verified): [tile(36)][wid(4)][mf(4)][lane(64)][kin(8)]
//   elem = tile*8192 + wid*2048 + mf*512 + lane*8 + kin; tile = pos*4+cib,
//   o = wid*64+mf*16+fl, lane = kpos*16+fl, ci = cib*32+kpos*8+kin.
// ---------------------------------------------------------------------------
__global__ __launch_bounds__(256) void build_weight(
    const float* __restrict__ dict, const float* __restrict__ coef,
    const int* __restrict__ idxw, unsigned short* __restrict__ wpack) {
    int o = blockIdx.x;
    int tid = threadIdx.x;
    bool mode64 = (idxw[1] == 0) && (idxw[3] == 0) && (idxw[5] == 0) &&
                  (idxw[7] == 0) && (idxw[9] == 0) && (idxw[11] == 0) &&
                  (idxw[13] == 0) && (idxw[15] == 0);
    float c[8]; int di[8];
#pragma unroll
    for (int s = 0; s < 8; ++s) {
        c[s]  = coef[o * 8 + s];
        di[s] = mode64 ? idxw[(o * 8 + s) * 2] : idxw[o * 8 + s];
    }
    const int wid = o >> 6, mf = (o >> 4) & 3, fl = o & 15;
    for (int j = tid; j < 9 * 128; j += 256) {
        int pos = j >> 7;          // 0..8
        int ci  = j & 127;
        int kh = pos / 3, kw = pos - kh * 3;
        float v = 0.f;
#pragma unroll
        for (int s = 0; s < 8; ++s)
            v += c[s] * dict[((di[s] * CIN + ci) * 3 + kh) * 3 + kw];
        int tile = pos * 4 + (ci >> 5);
        int kpos = (ci >> 3) & 3, kin = ci & 7;
        wpack[tile * 8192 + wid * 2048 + mf * 512 + (kpos * 16 + fl) * 8 + kin]
            = f2bf(v);
    }
}

// ---------------------------------------------------------------------------
// Main: FUSED pack + implicit-GEMM conv (R23 = R19 verbatim, the verified
// best at 78.3us total). Session map: 8 structural hypotheses tested
// (barrier removal R8, B-reg-pipelining R10, A-bandwidth R11, A-coalescing
// R13, mov-rotation R15, occupancy up R18 / down R11, pack-hiding R20/R21,
// 32x32 MFMA R22) — all null or negative vs this structure. Conv ~1000 TF
// = 49% of the 16x16 MFMA ceiling at 3 waves/SIMD: the plain-HIP plateau
// for this class of structure (the 8-phase escape needs 8-wave blocks,
// which the 128-unified-reg x 4-wave/SIMD budget cannot hold — R18).
//  - fused batched pack: lane = iw, wave = ci-quarter; 32 independent
//    loads -> one wait -> 4 conflict-free 16B LDS writes (R16/R17 lessons:
//    stride 512 for reads; lane=iw for writes; batched loads).
//  - slab [row(3)][ch(16)][iw(64)][kin(8)] stride 512, 0-conflict reads,
//    resident for the whole K-loop: ONE barrier per block (R14).
//  - A: direct global->reg from L2-hot wpack (R13 coalesced layout),
//    ping-pong sets, static index under unroll-2 cib (R15).
//  - (256,3): LDS 49.7 KB -> 3 blocks/CU; 80 arch + 64 AGPR, no spill.
// ---------------------------------------------------------------------------
__global__ __launch_bounds__(256, 3) void conv_mfma(
    const float* __restrict__ x,
    const unsigned short* __restrict__ wpack,
    float* __restrict__ out) {
    // slab: elem = (row*16 + ch)*512 + iw*8 + kin ; +128 pad (junk-col reads)
    __shared__ unsigned short Bl[3 * 16 * 512 + 128];

    int tid  = threadIdx.x;
    int lane = tid & 63;
    int wid  = tid >> 6;       // 0..3 = Cout slice of 64 (and ci-quarter in pack)

    // XCD-bijective swizzle: 1792 = 8 * 224; each XCD gets 4 consecutive b's
    int flat = blockIdx.x;
    int swz  = (flat & 7) * 224 + (flat >> 3);
    int b    = swz / 56;       // 0..31
    int oh   = swz % 56;       // output row

    const int klane = lane >> 4;   // k-group (0..3)
    const int fl    = lane & 15;

    // A-fragment base (coalesced): af(tile,mf) = ap0 + tile*8192 + mf*512 elems
    const unsigned short* ap0 = wpack + (size_t)wid * 2048 + lane * 8;

    // ---- issue A(tile 0) early: latency hides under the pack phase ----
    bf16x8 af[2][4];
#pragma unroll
    for (int mf = 0; mf < 4; ++mf)
        af[0][mf] = *(const bf16x8*)(ap0 + mf * 512);

    // ---- fused pack: lane = iw, wave = ci-quarter; batched 32-float loads ----
    {
        const int iw = lane;
        const bool vw = (iw >= 1) && (iw <= WW);
        const int w = vw ? iw - 1 : 0;
#pragma unroll
        for (int row = 0; row < 3; ++row) {
            int h = oh + row - 1;
            bool valid = vw && (h >= 0) && (h < HH);
            int hc = h < 0 ? 0 : (h >= HH ? HH - 1 : h);
            const float* px =
                x + (((size_t)b * CIN + wid * 32) * HH + hc) * WW + w;
            float v[32];
#pragma unroll
            for (int j = 0; j < 32; ++j)          // 32 independent loads
                v[j] = px[(size_t)j * (HH * WW)];
#pragma unroll
            for (int c = 0; c < 4; ++c) {         // one wait, 4 vector writes
                bf16x8 pv;
#pragma unroll
                for (int j = 0; j < 8; ++j)
                    pv[j] = valid ? (short)f2bf(v[c * 8 + j]) : (short)0;
                *(bf16x8*)&Bl[(row * 16 + wid * 4 + c) * 512 + iw * 8] = pv;
            }
        }
    }

    f32x4 acc[4][4];
    f32x4 zero = {0.f, 0.f, 0.f, 0.f};
#pragma unroll
    for (int i = 0; i < 4; ++i)
#pragma unroll
        for (int j = 0; j < 4; ++j) acc[i][j] = zero;

    __syncthreads();   // slab resident; ONLY barrier in the kernel

    const unsigned short* apc = ap0;                       // += 8192/cib
    const unsigned short* bl0 = &Bl[klane * 512 + fl * 8];

#pragma unroll 2
    for (int cib = 0; cib < 4; ++cib) {
        const unsigned short* bcur = bl0 + cib * 2048;     // 4 ch per cib

#pragma unroll
        for (int pos = 0; pos < 9; ++pos) {
            const int kh = pos / 3, kw = pos - kh * 3;
            const int cur = (cib + pos) & 1;   // STATIC under unroll-2 cib

            // ---- prefetch A(next step) into the free set (ping-pong) ----
            if (pos < 8) {
#pragma unroll
                for (int mf = 0; mf < 4; ++mf)
                    af[cur ^ 1][mf] =
                        *(const bf16x8*)(apc + (pos + 1) * 32768 + mf * 512);
            } else if (cib < 3) {
#pragma unroll
                for (int mf = 0; mf < 4; ++mf)
                    af[cur ^ 1][mf] = *(const bf16x8*)(apc + 8192 + mf * 512);
            }

            // ---- B fragments from resident slab (imm-offset ds_read) ----
            bf16x8 bfr[4];
#pragma unroll
            for (int nf = 0; nf < 4; ++nf)
                bfr[nf] = *(const bf16x8*)(bcur + kh * 8192 + (nf * 16 + kw) * 8);

            // ---- 16 MFMA on af[cur] (loaded a full step ago) ----
            __builtin_amdgcn_s_setprio(1);
#pragma unroll
            for (int mf = 0; mf < 4; ++mf)
#pragma unroll
                for (int nf = 0; nf < 4; ++nf)
                    acc[mf][nf] = __builtin_amdgcn_mfma_f32_16x16x32_bf16(
                        af[cur][mf], bfr[nf], acc[mf][nf], 0, 0, 0);
            __builtin_amdgcn_s_setprio(0);
        }
        apc += 8192;
    }

    // Epilogue: C/D layout col = lane&15, row = (lane>>4)*4 + reg (m89-verified)
#pragma unroll
    for (int nf = 0; nf < 4; ++nf) {
        int ow = nf * 16 + fl;
        if (ow < WW) {
#pragma unroll
            for (int mf = 0; mf < 4; ++mf) {
                int ob = wid * 64 + mf * 16 + (lane >> 4) * 4;
                float* dst = out + (((size_t)b * COUT + ob) * HH + oh) * WW + ow;
#pragma unroll
                for (int r = 0; r < 4; ++r)
                    dst[(size_t)r * HH * WW] = acc[mf][nf][r];
            }
        }
    }
}

extern "C" void kernel_launch(void* const* d_in, const int* in_sizes, int n_in,
                              void* d_out, int out_size, void* d_ws, size_t ws_size,
                              hipStream_t stream) {
    const float* x    = (const float*)d_in[0];
    const float* dict = (const float*)d_in[1];
    const float* coef = (const float*)d_in[2];
    const int*   idxw = (const int*)d_in[3];
    float* out = (float*)d_out;

    unsigned short* wpack = (unsigned short*)d_ws;

    build_weight<<<dim3(COUT), dim3(256), 0, stream>>>(dict, coef, idxw, wpack);
    conv_mfma<<<dim3(NB * 56), dim3(256), 0, stream>>>(x, wpack, out);
}